// Round 1
// baseline (644.509 us; speedup 1.0000x reference)
//
#include <hip/hip_runtime.h>

#define N 8192
#define K1 31              // K=30 -> k+1 = 31 kept per row/column
#define CAP 1024           // candidate capacity per line (row or col)
#define NB 2048            // global histogram bins (top 11 key bits)
#define HSHIFT 21
#define TARGET 76800u      // sampled suffix target; 4M samples, ~1.83% suffix (~150/line)

typedef unsigned int u32;
typedef unsigned long long u64;

// monotone fp32-bits -> u32 key (larger float => larger key)
__device__ __forceinline__ u32 fkey(u32 u) {
    return (u & 0x80000000u) ? ~u : (u | 0x80000000u);
}
// pack (key, idx): larger u64 = larger key, or equal key and SMALLER idx
__device__ __forceinline__ u64 pack_ki(u32 key, u32 idx) {
    return ((u64)key << 32) | (u32)(~idx);
}

// ============================================================================
// 0) zero the global histogram + column counters (ws is re-poisoned per call)
// ============================================================================
__global__ __launch_bounds__(256) void init_kernel(u32* __restrict__ hist,
                                                   u32* __restrict__ colcnt) {
    int i = blockIdx.x * 256 + threadIdx.x;
    if (i < NB) hist[i] = 0u;
    for (int j = i; j < N; j += (int)gridDim.x * 256) colcnt[j] = 0u;
}

// ============================================================================
// 1) sampled global histogram: 4M samples as coalesced float4 runs.
//    4096 runs of 256 uint4 (4 KB contiguous each), one run per (block,it),
//    rotated within each 64 KB segment so all column groups are covered.
//    4-way LDS sub-histograms cut same-bin atomic serialization.
// ============================================================================
__global__ __launch_bounds__(256) void sample_hist_kernel(const float* __restrict__ A,
                                                          u32* __restrict__ hist) {
    __shared__ u32 h[4][NB];
    const int tid = threadIdx.x;
    for (int b = tid; b < 4 * NB; b += 256) ((u32*)h)[b] = 0u;
    __syncthreads();
    const int sub = tid & 3;
    const uint4* A4 = (const uint4*)A;
#pragma unroll
    for (int it = 0; it < 16; ++it) {
        const int run = blockIdx.x * 16 + it;                       // 0..4095
        const size_t idx = (size_t)run * 4096 + (size_t)((run & 15) * 256) + tid;
        uint4 v = A4[idx];                                          // coalesced 4 KB/wave-pair
        atomicAdd(&h[sub][fkey(v.x) >> HSHIFT], 1u);
        atomicAdd(&h[sub][fkey(v.y) >> HSHIFT], 1u);
        atomicAdd(&h[sub][fkey(v.z) >> HSHIFT], 1u);
        atomicAdd(&h[sub][fkey(v.w) >> HSHIFT], 1u);
    }
    __syncthreads();
    for (int b = tid; b < NB; b += 256) {
        u32 s = h[0][b] + h[1][b] + h[2][b] + h[3][b];
        if (s) atomicAdd(&hist[b], s);
    }
}

// ============================================================================
// 2) pick conservative global key threshold g: largest bin base with
//    sampled suffix count >= TARGET. One block.
// ============================================================================
__global__ __launch_bounds__(256) void pick_g_kernel(const u32* __restrict__ hist,
                                                     u32* __restrict__ g_out) {
    __shared__ u32 suf[NB + 1];
    __shared__ u32 part[256];
    const int tid = threadIdx.x;
    u32 loc[8];
    u32 s = 0;
    for (int k = 7; k >= 0; --k) { s += hist[tid * 8 + k]; loc[k] = s; }
    part[tid] = s;
    __syncthreads();
    for (int off = 1; off < 256; off <<= 1) {        // inclusive suffix scan
        u32 add = (tid + off < 256) ? part[tid + off] : 0u;
        __syncthreads();
        part[tid] += add;
        __syncthreads();
    }
    u32 higher = (tid < 255) ? part[tid + 1] : 0u;
    for (int k = 0; k < 8; ++k) suf[tid * 8 + k] = loc[k] + higher;
    if (tid == 0) suf[NB] = 0u;
    __syncthreads();
    for (int k = 0; k < 8; ++k) {
        int b = tid * 8 + k;
        if (suf[b] >= TARGET && suf[b + 1] < TARGET)   // exactly one b (suf monotone)
            *g_out = (u32)b << HSHIFT;
    }
}

// ============================================================================
// 3) streaming extraction: one block per row. Every element with key >= g is
//    appended to its row list (LDS, flushed coalesced) and its column list
//    (global atomic slot). Counts written for exactness checks.
// ============================================================================
__global__ __launch_bounds__(256) void extract_kernel(
        const float* __restrict__ A, const u32* __restrict__ g_ptr,
        u64* __restrict__ rowcand, u64* __restrict__ colcand,
        u32* __restrict__ rowcnt, u32* __restrict__ colcnt) {
    __shared__ u64 buf[CAP];
    __shared__ u32 rc;
    const int tid = threadIdx.x;
    const int row = blockIdx.x;
    if (tid == 0) rc = 0u;
    __syncthreads();
    const u32 g = *g_ptr;
    const uint4* A4 = (const uint4*)(A + (size_t)row * N);
#pragma unroll
    for (int it = 0; it < 8; ++it) {
        uint4 v = A4[it * 256 + tid];
        const int j = (it * 256 + tid) * 4;
        u32 ks[4] = { fkey(v.x), fkey(v.y), fkey(v.z), fkey(v.w) };
#pragma unroll
        for (int q = 0; q < 4; ++q) {
            if (ks[q] >= g) {
                const int c = j + q;
                u32 slot = atomicAdd(&rc, 1u);
                if (slot < CAP) buf[slot] = pack_ki(ks[q], (u32)c);
                u32 cs = atomicAdd(&colcnt[c], 1u);
                if (cs < CAP) colcand[(size_t)c * CAP + cs] = pack_ki(ks[q], (u32)row);
            }
        }
    }
    __syncthreads();
    u32 n = rc < CAP ? rc : CAP;
    for (u32 s = tid; s < n; s += 256) rowcand[(size_t)row * CAP + s] = buf[s];
    if (tid == 0) rowcnt[row] = rc;
}

// ============================================================================
// 4) exact select from candidates: 31st-largest (key,idx) via pairwise rank.
//    Flags lines needing the fallback (cnt<31 or overflow).
// ============================================================================
__global__ __launch_bounds__(256) void rank_select_kernel(
        const u64* __restrict__ cand, const u32* __restrict__ cnts,
        u32* __restrict__ t_out, int* __restrict__ L_out, u32* __restrict__ flag) {
    __shared__ u64 buf[CAP];
    const int line = blockIdx.x;
    const int tid  = threadIdx.x;
    const u32 cnt  = cnts[line];
    if (cnt < (u32)K1 || cnt > (u32)CAP) {
        if (tid == 0) flag[line] = 1u;
        return;
    }
    if (tid == 0) flag[line] = 0u;
    for (u32 s = tid; s < cnt; s += 256) buf[s] = cand[(size_t)line * CAP + s];
    __syncthreads();
    for (u32 s = tid; s < cnt; s += 256) {
        const u64 mine = buf[s];
        u32 r = 0;
        for (u32 q = 0; q < cnt; ++q) r += (buf[q] > mine) ? 1u : 0u;  // LDS broadcast
        if (r == (u32)(K1 - 1)) {
            t_out[line] = (u32)(mine >> 32);
            L_out[line] = (int)(~(u32)mine);
        }
    }
}

// ============================================================================
// 5) exact fallback (rare: early-exits on clear flag). Full LDS radix-256
//    select over 32-bit keys + binary-searched tie index L. Works for rows
//    (rstride=N, estride=1) and columns (rstride=1, estride=N).
// ============================================================================
__global__ __launch_bounds__(256) void fallback_select_kernel(
        const float* __restrict__ A, const u32* __restrict__ flag,
        long rstride, long estride, u32* __restrict__ t_out, int* __restrict__ L_out) {
    if (flag[blockIdx.x] == 0u) return;
    __shared__ u32 keys[N];            // 32 KB
    __shared__ u32 hist[4][256];
    __shared__ u32 scanb[256];
    __shared__ u32 sh_sel, sh_want, sh_gt, sh_cnt;

    const int tid  = threadIdx.x;
    const int wave = tid >> 6;
    const size_t base = (size_t)blockIdx.x * (size_t)rstride;

    for (int it = 0; it < N / 256; ++it) {
        int j = it * 256 + tid;
        keys[j] = fkey(__float_as_uint(A[base + (size_t)j * (size_t)estride]));
    }
    if (tid == 0) { sh_sel = 0u; sh_want = (u32)K1; sh_gt = 0u; }
    __syncthreads();

    for (int pass = 3; pass >= 0; --pass) {
        const u32 pref = sh_sel;
        const u32 want = sh_want;
        hist[0][tid] = 0u; hist[1][tid] = 0u; hist[2][tid] = 0u; hist[3][tid] = 0u;
        __syncthreads();
        const u32 pmask = (pass == 3) ? 0u : (0xFFFFFFFFu << ((pass + 1) * 8));
        const int shift = pass * 8;
        for (int it = 0; it < N / 256; ++it) {
            u32 k = keys[it * 256 + tid];
            if ((k & pmask) == (pref & pmask))
                atomicAdd(&hist[wave][(k >> shift) & 0xFFu], 1u);
        }
        __syncthreads();
        scanb[tid] = hist[0][tid] + hist[1][tid] + hist[2][tid] + hist[3][tid];
        __syncthreads();
        for (int off = 1; off < 256; off <<= 1) {
            u32 add = (tid + off < 256) ? scanb[tid + off] : 0u;
            __syncthreads();
            scanb[tid] += add;
            __syncthreads();
        }
        u32 incl = scanb[tid];
        u32 abov = (tid < 255) ? scanb[tid + 1] : 0u;
        if (incl >= want && abov < want) {
            sh_sel  = pref | ((u32)tid << shift);
            sh_want = want - abov;
        }
        __syncthreads();
    }
    const u32 tkey = sh_sel;

    u32 my = 0;
    for (int it = 0; it < N / 256; ++it) my += (keys[it * 256 + tid] > tkey) ? 1u : 0u;
    atomicAdd(&sh_gt, my);
    __syncthreads();
    const int m = K1 - (int)sh_gt;     // ties to accept, >= 1

    // binary search smallest X with #(ties at idx<=X) >= m  -> L = X
    int lo = 0, hi = N - 1;
    while (lo < hi) {
        int mid = (lo + hi) >> 1;
        if (tid == 0) sh_cnt = 0u;
        __syncthreads();
        u32 c = 0;
        for (int it = 0; it < N / 256; ++it) {
            int j = it * 256 + tid;
            c += (keys[j] == tkey && j <= mid) ? 1u : 0u;
        }
        atomicAdd(&sh_cnt, c);
        __syncthreads();
        if ((int)sh_cnt >= m) hi = mid; else lo = mid + 1;
        __syncthreads();               // protect sh_cnt reuse
    }
    if (tid == 0) { t_out[blockIdx.x] = tkey; L_out[blockIdx.x] = lo; }
}

// ============================================================================
// 6) mask: out[i,j] = A[i,j] iff top31(row i) && top31(col j) && i != j.
// ============================================================================
__global__ __launch_bounds__(256) void mask_kernel(
        const float* __restrict__ A,
        const u32* __restrict__ tk_r, const int* __restrict__ L_r,
        const u32* __restrict__ tk_c, const int* __restrict__ L_c,
        float* __restrict__ out) {
    const u32 gid = blockIdx.x * 256u + threadIdx.x;   // float4 units
    const int i  = (int)(gid >> 11);                   // 2048 float4 per row
    const int j0 = (int)(gid & 2047u) << 2;

    uint4 v = ((const uint4*)A)[gid];
    const u32 tr = tk_r[i];
    const int lr = L_r[i];
    uint4 tc = *(const uint4*)(tk_c + j0);
    int4  lc = *(const int4*)(L_c + j0);

    auto keep = [&](u32 bits, int j, u32 tcv, int lcv) -> u32 {
        u32 k = fkey(bits);
        bool rok = (k > tr)  || (k == tr  && j <= lr);
        bool cok = (k > tcv) || (k == tcv && i <= lcv);
        return (rok && cok && (i != j)) ? bits : 0u;
    };

    uint4 o;
    o.x = keep(v.x, j0 + 0, tc.x, lc.x);
    o.y = keep(v.y, j0 + 1, tc.y, lc.y);
    o.z = keep(v.z, j0 + 2, tc.z, lc.z);
    o.w = keep(v.w, j0 + 3, tc.w, lc.w);
    ((uint4*)out)[gid] = o;
}

// ============================================================================
extern "C" void kernel_launch(void* const* d_in, const int* in_sizes, int n_in,
                              void* d_out, int out_size, void* d_ws, size_t ws_size,
                              hipStream_t stream) {
    const float* A   = (const float*)d_in[0];
    float*       out = (float*)d_out;

    // ---- small arrays in ws (~300 KB) ----
    u32* hist   = (u32*)d_ws;            // NB
    u32* g_key  = hist + NB;             // 1 (+pad to 64)
    u32* rowcnt = g_key + 64;            // N
    u32* colcnt = rowcnt + N;            // N
    u32* rowflg = colcnt + N;            // N
    u32* colflg = rowflg + N;            // N
    u32* tk_r   = colflg + N;            // N
    int* L_r    = (int*)(tk_r + N);      // N
    u32* tk_c   = (u32*)(L_r + N);       // N
    int* L_c    = (int*)(tk_c + N);      // N

    // ---- candidate lists live in d_out (consumed before mask overwrites) ----
    u64* rowcand = (u64*)d_out;                          // N*CAP*8 = 64 MB
    u64* colcand = rowcand + (size_t)N * CAP;            // 64 MB

    init_kernel<<<dim3(32), dim3(256), 0, stream>>>(hist, colcnt);
    sample_hist_kernel<<<dim3(256), dim3(256), 0, stream>>>(A, hist);
    pick_g_kernel<<<dim3(1), dim3(256), 0, stream>>>(hist, g_key);
    extract_kernel<<<dim3(N), dim3(256), 0, stream>>>(A, g_key, rowcand, colcand,
                                                      rowcnt, colcnt);
    rank_select_kernel<<<dim3(N), dim3(256), 0, stream>>>(rowcand, rowcnt, tk_r, L_r, rowflg);
    rank_select_kernel<<<dim3(N), dim3(256), 0, stream>>>(colcand, colcnt, tk_c, L_c, colflg);
    fallback_select_kernel<<<dim3(N), dim3(256), 0, stream>>>(A, rowflg, (long)N, 1L, tk_r, L_r);
    fallback_select_kernel<<<dim3(N), dim3(256), 0, stream>>>(A, colflg, 1L, (long)N, tk_c, L_c);
    mask_kernel<<<dim3((u32)((size_t)N * N / 4 / 256)), dim3(256), 0, stream>>>(
        A, tk_r, L_r, tk_c, L_c, out);
}

// Round 2
// 568.172 us; speedup vs baseline: 1.1344x; 1.1344x over previous
//
#include <hip/hip_runtime.h>

#define N 8192
#define K1 31              // K=30 -> k+1 = 31 kept per row/column
#define CAP 1024           // candidate capacity per line (row or col)
#define NB 2048            // global histogram bins (top 11 key bits)
#define HSHIFT 21
#define TARGET 76800u      // sampled suffix target; 4M samples, ~1.83% suffix (~150/line)
#define CSTRIDE 16         // colcnt padded: one u32 counter per 64B line

typedef unsigned int u32;
typedef unsigned long long u64;

// monotone fp32-bits -> u32 key (larger float => larger key)
__device__ __forceinline__ u32 fkey(u32 u) {
    return (u & 0x80000000u) ? ~u : (u | 0x80000000u);
}
// pack (key, idx): larger u64 = larger key, or equal key and SMALLER idx
__device__ __forceinline__ u64 pack_ki(u32 key, u32 idx) {
    return ((u64)key << 32) | (u32)(~idx);
}

// ============================================================================
// 0) zero the global histogram + padded column counters
// ============================================================================
__global__ __launch_bounds__(256) void init_kernel(u32* __restrict__ hist,
                                                   u32* __restrict__ colcnt_pad) {
    int i = blockIdx.x * 256 + threadIdx.x;
    if (i < NB) hist[i] = 0u;
    for (int j = i; j < N * CSTRIDE; j += (int)gridDim.x * 256) colcnt_pad[j] = 0u;
}

// ============================================================================
// 1) sampled global histogram: 4M samples as coalesced float4 runs.
//    4096 runs of 256 uint4 (4 KB contiguous each), rotated within each
//    64 KB segment so all column groups are covered. 4-way LDS sub-hists.
// ============================================================================
__global__ __launch_bounds__(256) void sample_hist_kernel(const float* __restrict__ A,
                                                          u32* __restrict__ hist) {
    __shared__ u32 h[4][NB];
    const int tid = threadIdx.x;
    for (int b = tid; b < 4 * NB; b += 256) ((u32*)h)[b] = 0u;
    __syncthreads();
    const int sub = tid & 3;
    const uint4* A4 = (const uint4*)A;
#pragma unroll
    for (int it = 0; it < 16; ++it) {
        const int run = blockIdx.x * 16 + it;                       // 0..4095
        const size_t idx = (size_t)run * 4096 + (size_t)((run & 15) * 256) + tid;
        uint4 v = A4[idx];                                          // coalesced
        atomicAdd(&h[sub][fkey(v.x) >> HSHIFT], 1u);
        atomicAdd(&h[sub][fkey(v.y) >> HSHIFT], 1u);
        atomicAdd(&h[sub][fkey(v.z) >> HSHIFT], 1u);
        atomicAdd(&h[sub][fkey(v.w) >> HSHIFT], 1u);
    }
    __syncthreads();
    for (int b = tid; b < NB; b += 256) {
        u32 s = h[0][b] + h[1][b] + h[2][b] + h[3][b];
        if (s) atomicAdd(&hist[b], s);
    }
}

// ============================================================================
// 2) pick conservative global key threshold g: largest bin base with
//    sampled suffix count >= TARGET. One block.
// ============================================================================
__global__ __launch_bounds__(256) void pick_g_kernel(const u32* __restrict__ hist,
                                                     u32* __restrict__ g_out) {
    __shared__ u32 suf[NB + 1];
    __shared__ u32 part[256];
    const int tid = threadIdx.x;
    u32 loc[8];
    u32 s = 0;
    for (int k = 7; k >= 0; --k) { s += hist[tid * 8 + k]; loc[k] = s; }
    part[tid] = s;
    __syncthreads();
    for (int off = 1; off < 256; off <<= 1) {        // inclusive suffix scan
        u32 add = (tid + off < 256) ? part[tid + off] : 0u;
        __syncthreads();
        part[tid] += add;
        __syncthreads();
    }
    u32 higher = (tid < 255) ? part[tid + 1] : 0u;
    for (int k = 0; k < 8; ++k) suf[tid * 8 + k] = loc[k] + higher;
    if (tid == 0) suf[NB] = 0u;
    __syncthreads();
    for (int k = 0; k < 8; ++k) {
        int b = tid * 8 + k;
        if (suf[b] >= TARGET && suf[b + 1] < TARGET)   // exactly one b (suf monotone)
            *g_out = (u32)b << HSHIFT;
    }
}

// ============================================================================
// 3) streaming extraction: one block per row. Streaming loop is pure
//    read + LDS append (8 loads in flight). Column entries are emitted in a
//    tail loop from the LDS buffer (<=1 padded-line atomic per thread).
//    Row-overflow hits emit their column entry inline so colcnt stays exact.
// ============================================================================
__global__ __launch_bounds__(256) void extract_kernel(
        const float* __restrict__ A, const u32* __restrict__ g_ptr,
        u64* __restrict__ rowcand, u64* __restrict__ colcand,
        u32* __restrict__ rowcnt, u32* __restrict__ colcnt_pad) {
    __shared__ u64 buf[CAP];
    __shared__ u32 rc;
    const int tid = threadIdx.x;
    const int row = blockIdx.x;
    if (tid == 0) rc = 0u;
    __syncthreads();
    const u32 g = *g_ptr;
    const uint4* A4 = (const uint4*)(A + (size_t)row * N);
    uint4 v[8];
#pragma unroll
    for (int it = 0; it < 8; ++it) v[it] = A4[it * 256 + tid];   // 8 loads in flight
#pragma unroll
    for (int it = 0; it < 8; ++it) {
        const int j = (it * 256 + tid) * 4;
        u32 ks[4] = { fkey(v[it].x), fkey(v[it].y), fkey(v[it].z), fkey(v[it].w) };
#pragma unroll
        for (int q = 0; q < 4; ++q) {
            if (ks[q] >= g) {
                u32 slot = atomicAdd(&rc, 1u);
                if (slot < CAP) {
                    buf[slot] = pack_ki(ks[q], (u32)(j + q));
                } else {
                    // row buffer overflow (row gets fallback via rowcnt>CAP);
                    // still emit the column entry so column lists stay exact
                    const int c = j + q;
                    u32 cs = atomicAdd(&colcnt_pad[(size_t)c * CSTRIDE], 1u);
                    if (cs < CAP) colcand[(size_t)c * CAP + cs] = pack_ki(ks[q], (u32)row);
                }
            }
        }
    }
    __syncthreads();
    const u32 n = rc < CAP ? rc : CAP;
    for (u32 s = tid; s < n; s += 256) {
        const u64 e = buf[s];
        rowcand[(size_t)row * CAP + s] = e;
        const u32 key = (u32)(e >> 32);
        const u32 c   = ~(u32)e;
        u32 cs = atomicAdd(&colcnt_pad[(size_t)c * CSTRIDE], 1u);
        if (cs < CAP) colcand[(size_t)c * CAP + cs] = pack_ki(key, (u32)row);
    }
    if (tid == 0) rowcnt[row] = rc;
}

// ============================================================================
// 4) exact select from candidates: 31st-largest (key,idx) via pairwise rank.
//    Flags lines needing the fallback (cnt<31 or overflow). cnts strided to
//    support the padded column counters.
// ============================================================================
__global__ __launch_bounds__(256) void rank_select_kernel(
        const u64* __restrict__ cand, const u32* __restrict__ cnts, int cstride,
        u32* __restrict__ t_out, int* __restrict__ L_out, u32* __restrict__ flag) {
    __shared__ u64 buf[CAP];
    const int line = blockIdx.x;
    const int tid  = threadIdx.x;
    const u32 cnt  = cnts[(size_t)line * cstride];
    if (cnt < (u32)K1 || cnt > (u32)CAP) {
        if (tid == 0) flag[line] = 1u;
        return;
    }
    if (tid == 0) flag[line] = 0u;
    for (u32 s = tid; s < cnt; s += 256) buf[s] = cand[(size_t)line * CAP + s];
    __syncthreads();
    for (u32 s = tid; s < cnt; s += 256) {
        const u64 mine = buf[s];
        u32 r = 0;
        for (u32 q = 0; q < cnt; ++q) r += (buf[q] > mine) ? 1u : 0u;  // LDS broadcast
        if (r == (u32)(K1 - 1)) {
            t_out[line] = (u32)(mine >> 32);
            L_out[line] = (int)(~(u32)mine);
        }
    }
}

// ============================================================================
// 5) exact fallback (rare: early-exits on clear flag). Full LDS radix-256
//    select over 32-bit keys + binary-searched tie index L. Works for rows
//    (rstride=N, estride=1) and columns (rstride=1, estride=N).
// ============================================================================
__global__ __launch_bounds__(256) void fallback_select_kernel(
        const float* __restrict__ A, const u32* __restrict__ flag,
        long rstride, long estride, u32* __restrict__ t_out, int* __restrict__ L_out) {
    if (flag[blockIdx.x] == 0u) return;
    __shared__ u32 keys[N];            // 32 KB
    __shared__ u32 hist[4][256];
    __shared__ u32 scanb[256];
    __shared__ u32 sh_sel, sh_want, sh_gt, sh_cnt;

    const int tid  = threadIdx.x;
    const int wave = tid >> 6;
    const size_t base = (size_t)blockIdx.x * (size_t)rstride;

    for (int it = 0; it < N / 256; ++it) {
        int j = it * 256 + tid;
        keys[j] = fkey(__float_as_uint(A[base + (size_t)j * (size_t)estride]));
    }
    if (tid == 0) { sh_sel = 0u; sh_want = (u32)K1; sh_gt = 0u; }
    __syncthreads();

    for (int pass = 3; pass >= 0; --pass) {
        const u32 pref = sh_sel;
        const u32 want = sh_want;
        hist[0][tid] = 0u; hist[1][tid] = 0u; hist[2][tid] = 0u; hist[3][tid] = 0u;
        __syncthreads();
        const u32 pmask = (pass == 3) ? 0u : (0xFFFFFFFFu << ((pass + 1) * 8));
        const int shift = pass * 8;
        for (int it = 0; it < N / 256; ++it) {
            u32 k = keys[it * 256 + tid];
            if ((k & pmask) == (pref & pmask))
                atomicAdd(&hist[wave][(k >> shift) & 0xFFu], 1u);
        }
        __syncthreads();
        scanb[tid] = hist[0][tid] + hist[1][tid] + hist[2][tid] + hist[3][tid];
        __syncthreads();
        for (int off = 1; off < 256; off <<= 1) {
            u32 add = (tid + off < 256) ? scanb[tid + off] : 0u;
            __syncthreads();
            scanb[tid] += add;
            __syncthreads();
        }
        u32 incl = scanb[tid];
        u32 abov = (tid < 255) ? scanb[tid + 1] : 0u;
        if (incl >= want && abov < want) {
            sh_sel  = pref | ((u32)tid << shift);
            sh_want = want - abov;
        }
        __syncthreads();
    }
    const u32 tkey = sh_sel;

    u32 my = 0;
    for (int it = 0; it < N / 256; ++it) my += (keys[it * 256 + tid] > tkey) ? 1u : 0u;
    atomicAdd(&sh_gt, my);
    __syncthreads();
    const int m = K1 - (int)sh_gt;     // ties to accept, >= 1

    // binary search smallest X with #(ties at idx<=X) >= m  -> L = X
    int lo = 0, hi = N - 1;
    while (lo < hi) {
        int mid = (lo + hi) >> 1;
        if (tid == 0) sh_cnt = 0u;
        __syncthreads();
        u32 c = 0;
        for (int it = 0; it < N / 256; ++it) {
            int j = it * 256 + tid;
            c += (keys[j] == tkey && j <= mid) ? 1u : 0u;
        }
        atomicAdd(&sh_cnt, c);
        __syncthreads();
        if ((int)sh_cnt >= m) hi = mid; else lo = mid + 1;
        __syncthreads();               // protect sh_cnt reuse
    }
    if (tid == 0) { t_out[blockIdx.x] = tkey; L_out[blockIdx.x] = lo; }
}

// ============================================================================
// 6) mask: out[i,j] = A[i,j] iff top31(row i) && top31(col j) && i != j.
// ============================================================================
__global__ __launch_bounds__(256) void mask_kernel(
        const float* __restrict__ A,
        const u32* __restrict__ tk_r, const int* __restrict__ L_r,
        const u32* __restrict__ tk_c, const int* __restrict__ L_c,
        float* __restrict__ out) {
    const u32 gid = blockIdx.x * 256u + threadIdx.x;   // float4 units
    const int i  = (int)(gid >> 11);                   // 2048 float4 per row
    const int j0 = (int)(gid & 2047u) << 2;

    uint4 v = ((const uint4*)A)[gid];
    const u32 tr = tk_r[i];
    const int lr = L_r[i];
    uint4 tc = *(const uint4*)(tk_c + j0);
    int4  lc = *(const int4*)(L_c + j0);

    auto keep = [&](u32 bits, int j, u32 tcv, int lcv) -> u32 {
        u32 k = fkey(bits);
        bool rok = (k > tr)  || (k == tr  && j <= lr);
        bool cok = (k > tcv) || (k == tcv && i <= lcv);
        return (rok && cok && (i != j)) ? bits : 0u;
    };

    uint4 o;
    o.x = keep(v.x, j0 + 0, tc.x, lc.x);
    o.y = keep(v.y, j0 + 1, tc.y, lc.y);
    o.z = keep(v.z, j0 + 2, tc.z, lc.z);
    o.w = keep(v.w, j0 + 3, tc.w, lc.w);
    ((uint4*)out)[gid] = o;
}

// ============================================================================
extern "C" void kernel_launch(void* const* d_in, const int* in_sizes, int n_in,
                              void* d_out, int out_size, void* d_ws, size_t ws_size,
                              hipStream_t stream) {
    const float* A   = (const float*)d_in[0];
    float*       out = (float*)d_out;

    // ---- small arrays in ws (~260 KB) ----
    u32* hist   = (u32*)d_ws;            // NB
    u32* g_key  = hist + NB;             // 1 (+pad to 64)
    u32* rowcnt = g_key + 64;            // N
    u32* rowflg = rowcnt + N;            // N
    u32* colflg = rowflg + N;            // N
    u32* tk_r   = colflg + N;            // N
    int* L_r    = (int*)(tk_r + N);      // N
    u32* tk_c   = (u32*)(L_r + N);       // N
    int* L_c    = (int*)(tk_c + N);      // N

    // ---- candidate lists + padded colcnt live in d_out (consumed before mask) ----
    u64* rowcand    = (u64*)d_out;                               // 64 MB
    u64* colcand    = rowcand + (size_t)N * CAP;                 // 64 MB
    u32* colcnt_pad = (u32*)((char*)d_out + (size_t)128 * 1024 * 1024);  // 512 KB

    init_kernel<<<dim3(128), dim3(256), 0, stream>>>(hist, colcnt_pad);
    sample_hist_kernel<<<dim3(256), dim3(256), 0, stream>>>(A, hist);
    pick_g_kernel<<<dim3(1), dim3(256), 0, stream>>>(hist, g_key);
    extract_kernel<<<dim3(N), dim3(256), 0, stream>>>(A, g_key, rowcand, colcand,
                                                      rowcnt, colcnt_pad);
    rank_select_kernel<<<dim3(N), dim3(256), 0, stream>>>(rowcand, rowcnt, 1, tk_r, L_r, rowflg);
    rank_select_kernel<<<dim3(N), dim3(256), 0, stream>>>(colcand, colcnt_pad, CSTRIDE, tk_c, L_c, colflg);
    fallback_select_kernel<<<dim3(N), dim3(256), 0, stream>>>(A, rowflg, (long)N, 1L, tk_r, L_r);
    fallback_select_kernel<<<dim3(N), dim3(256), 0, stream>>>(A, colflg, 1L, (long)N, tk_c, L_c);
    mask_kernel<<<dim3((u32)((size_t)N * N / 4 / 256)), dim3(256), 0, stream>>>(
        A, tk_r, L_r, tk_c, L_c, out);
}

// Round 3
// 542.895 us; speedup vs baseline: 1.1872x; 1.0466x over previous
//
#include <hip/hip_runtime.h>

#define N 8192
#define K1 31              // K=30 -> k+1 = 31 kept per row/column
#define CAP 1024           // candidate capacity per line (row or col)
#define NB 2048            // global histogram bins (top 11 key bits)
#define HSHIFT 21
#define TARGET 76800u      // sampled suffix target; 4M samples, ~1.83% suffix (~150/line)
#define CSTRIDE 16         // colcnt padded: one u32 counter per 64B line

typedef unsigned int u32;
typedef unsigned long long u64;

// monotone fp32-bits -> u32 key (larger float => larger key)
__device__ __forceinline__ u32 fkey(u32 u) {
    return (u & 0x80000000u) ? ~u : (u | 0x80000000u);
}
// inverse of fkey (exact bit recovery of the original float)
__device__ __forceinline__ u32 fkey_inv(u32 k) {
    return (k & 0x80000000u) ? (k ^ 0x80000000u) : ~k;
}
// pack (key, idx): larger u64 = larger key, or equal key and SMALLER idx
__device__ __forceinline__ u64 pack_ki(u32 key, u32 idx) {
    return ((u64)key << 32) | (u32)(~idx);
}

// ============================================================================
// 0) zero the global histogram + padded column counters
// ============================================================================
__global__ __launch_bounds__(256) void init_kernel(u32* __restrict__ hist,
                                                   u32* __restrict__ colcnt_pad) {
    int i = blockIdx.x * 256 + threadIdx.x;
    if (i < NB) hist[i] = 0u;
    for (int j = i; j < N * CSTRIDE; j += (int)gridDim.x * 256) colcnt_pad[j] = 0u;
}

// ============================================================================
// 1) sampled global histogram: 4M samples as coalesced float4 runs.
//    4096 runs of 256 uint4 (4 KB contiguous each), rotated within each
//    64 KB segment so all column groups are covered. 4-way LDS sub-hists.
// ============================================================================
__global__ __launch_bounds__(256) void sample_hist_kernel(const float* __restrict__ A,
                                                          u32* __restrict__ hist) {
    __shared__ u32 h[4][NB];
    const int tid = threadIdx.x;
    for (int b = tid; b < 4 * NB; b += 256) ((u32*)h)[b] = 0u;
    __syncthreads();
    const int sub = tid & 3;
    const uint4* A4 = (const uint4*)A;
#pragma unroll
    for (int it = 0; it < 16; ++it) {
        const int run = blockIdx.x * 16 + it;                       // 0..4095
        const size_t idx = (size_t)run * 4096 + (size_t)((run & 15) * 256) + tid;
        uint4 v = A4[idx];                                          // coalesced
        atomicAdd(&h[sub][fkey(v.x) >> HSHIFT], 1u);
        atomicAdd(&h[sub][fkey(v.y) >> HSHIFT], 1u);
        atomicAdd(&h[sub][fkey(v.z) >> HSHIFT], 1u);
        atomicAdd(&h[sub][fkey(v.w) >> HSHIFT], 1u);
    }
    __syncthreads();
    for (int b = tid; b < NB; b += 256) {
        u32 s = h[0][b] + h[1][b] + h[2][b] + h[3][b];
        if (s) atomicAdd(&hist[b], s);
    }
}

// ============================================================================
// 2) pick conservative global key threshold g: largest bin base with
//    sampled suffix count >= TARGET. One block.
// ============================================================================
__global__ __launch_bounds__(256) void pick_g_kernel(const u32* __restrict__ hist,
                                                     u32* __restrict__ g_out) {
    __shared__ u32 suf[NB + 1];
    __shared__ u32 part[256];
    const int tid = threadIdx.x;
    u32 loc[8];
    u32 s = 0;
    for (int k = 7; k >= 0; --k) { s += hist[tid * 8 + k]; loc[k] = s; }
    part[tid] = s;
    __syncthreads();
    for (int off = 1; off < 256; off <<= 1) {        // inclusive suffix scan
        u32 add = (tid + off < 256) ? part[tid + off] : 0u;
        __syncthreads();
        part[tid] += add;
        __syncthreads();
    }
    u32 higher = (tid < 255) ? part[tid + 1] : 0u;
    for (int k = 0; k < 8; ++k) suf[tid * 8 + k] = loc[k] + higher;
    if (tid == 0) suf[NB] = 0u;
    __syncthreads();
    for (int k = 0; k < 8; ++k) {
        int b = tid * 8 + k;
        if (suf[b] >= TARGET && suf[b + 1] < TARGET)   // exactly one b (suf monotone)
            *g_out = (u32)b << HSHIFT;
    }
}

// ============================================================================
// 3) streaming extraction + output pre-zero: one block per row. Streams the
//    row of A (8 loads in flight), zero-fills the same row of out (stores
//    overlap the latency-bound candidate phase), appends hits to LDS, then a
//    tail loop emits column entries (<=1 padded-line atomic per thread).
//    Row-overflow hits emit their column entry inline so colcnt stays exact.
// ============================================================================
__global__ __launch_bounds__(256) void extract_kernel(
        const float* __restrict__ A, const u32* __restrict__ g_ptr,
        u64* __restrict__ rowcand, u64* __restrict__ colcand,
        u32* __restrict__ rowcnt, u32* __restrict__ colcnt_pad,
        float* __restrict__ out) {
    __shared__ u64 buf[CAP];
    __shared__ u32 rc;
    const int tid = threadIdx.x;
    const int row = blockIdx.x;
    if (tid == 0) rc = 0u;
    __syncthreads();
    const u32 g = *g_ptr;
    const uint4* A4 = (const uint4*)(A + (size_t)row * N);
    uint4* O4 = (uint4*)(out + (size_t)row * N);
    uint4 v[8];
#pragma unroll
    for (int it = 0; it < 8; ++it) v[it] = A4[it * 256 + tid];   // 8 loads in flight
    const uint4 z = make_uint4(0u, 0u, 0u, 0u);
#pragma unroll
    for (int it = 0; it < 8; ++it) O4[it * 256 + tid] = z;       // pre-zero out row
#pragma unroll
    for (int it = 0; it < 8; ++it) {
        const int j = (it * 256 + tid) * 4;
        u32 ks[4] = { fkey(v[it].x), fkey(v[it].y), fkey(v[it].z), fkey(v[it].w) };
#pragma unroll
        for (int q = 0; q < 4; ++q) {
            if (ks[q] >= g) {
                u32 slot = atomicAdd(&rc, 1u);
                if (slot < CAP) {
                    buf[slot] = pack_ki(ks[q], (u32)(j + q));
                } else {
                    // row buffer overflow (row gets fallback via rowcnt>CAP);
                    // still emit the column entry so column lists stay exact
                    const int c = j + q;
                    u32 cs = atomicAdd(&colcnt_pad[(size_t)c * CSTRIDE], 1u);
                    if (cs < CAP) colcand[(size_t)c * CAP + cs] = pack_ki(ks[q], (u32)row);
                }
            }
        }
    }
    __syncthreads();
    const u32 n = rc < CAP ? rc : CAP;
    for (u32 s = tid; s < n; s += 256) {
        const u64 e = buf[s];
        rowcand[(size_t)row * CAP + s] = e;
        const u32 key = (u32)(e >> 32);
        const u32 c   = ~(u32)e;
        u32 cs = atomicAdd(&colcnt_pad[(size_t)c * CSTRIDE], 1u);
        if (cs < CAP) colcand[(size_t)c * CAP + cs] = pack_ki(key, (u32)row);
    }
    if (tid == 0) rowcnt[row] = rc;
}

// ============================================================================
// 4) exact select from candidates: 31st-largest (key,idx) via pairwise rank.
//    Flags lines needing the fallback (cnt<31 or overflow). cnts strided to
//    support the padded column counters.
// ============================================================================
__global__ __launch_bounds__(256) void rank_select_kernel(
        const u64* __restrict__ cand, const u32* __restrict__ cnts, int cstride,
        u32* __restrict__ t_out, int* __restrict__ L_out, u32* __restrict__ flag) {
    __shared__ u64 buf[CAP];
    const int line = blockIdx.x;
    const int tid  = threadIdx.x;
    const u32 cnt  = cnts[(size_t)line * cstride];
    if (cnt < (u32)K1 || cnt > (u32)CAP) {
        if (tid == 0) flag[line] = 1u;
        return;
    }
    if (tid == 0) flag[line] = 0u;
    for (u32 s = tid; s < cnt; s += 256) buf[s] = cand[(size_t)line * CAP + s];
    __syncthreads();
    for (u32 s = tid; s < cnt; s += 256) {
        const u64 mine = buf[s];
        u32 r = 0;
        for (u32 q = 0; q < cnt; ++q) r += (buf[q] > mine) ? 1u : 0u;  // LDS broadcast
        if (r == (u32)(K1 - 1)) {
            t_out[line] = (u32)(mine >> 32);
            L_out[line] = (int)(~(u32)mine);
        }
    }
}

// ============================================================================
// 5) exact fallback (rare: early-exits on clear flag). Full LDS radix-256
//    select over 32-bit keys + binary-searched tie index L. Works for rows
//    (rstride=N, estride=1) and columns (rstride=1, estride=N).
// ============================================================================
__global__ __launch_bounds__(256) void fallback_select_kernel(
        const float* __restrict__ A, const u32* __restrict__ flag,
        long rstride, long estride, u32* __restrict__ t_out, int* __restrict__ L_out) {
    if (flag[blockIdx.x] == 0u) return;
    __shared__ u32 keys[N];            // 32 KB
    __shared__ u32 hist[4][256];
    __shared__ u32 scanb[256];
    __shared__ u32 sh_sel, sh_want, sh_gt, sh_cnt;

    const int tid  = threadIdx.x;
    const int wave = tid >> 6;
    const size_t base = (size_t)blockIdx.x * (size_t)rstride;

    for (int it = 0; it < N / 256; ++it) {
        int j = it * 256 + tid;
        keys[j] = fkey(__float_as_uint(A[base + (size_t)j * (size_t)estride]));
    }
    if (tid == 0) { sh_sel = 0u; sh_want = (u32)K1; sh_gt = 0u; }
    __syncthreads();

    for (int pass = 3; pass >= 0; --pass) {
        const u32 pref = sh_sel;
        const u32 want = sh_want;
        hist[0][tid] = 0u; hist[1][tid] = 0u; hist[2][tid] = 0u; hist[3][tid] = 0u;
        __syncthreads();
        const u32 pmask = (pass == 3) ? 0u : (0xFFFFFFFFu << ((pass + 1) * 8));
        const int shift = pass * 8;
        for (int it = 0; it < N / 256; ++it) {
            u32 k = keys[it * 256 + tid];
            if ((k & pmask) == (pref & pmask))
                atomicAdd(&hist[wave][(k >> shift) & 0xFFu], 1u);
        }
        __syncthreads();
        scanb[tid] = hist[0][tid] + hist[1][tid] + hist[2][tid] + hist[3][tid];
        __syncthreads();
        for (int off = 1; off < 256; off <<= 1) {
            u32 add = (tid + off < 256) ? scanb[tid + off] : 0u;
            __syncthreads();
            scanb[tid] += add;
            __syncthreads();
        }
        u32 incl = scanb[tid];
        u32 abov = (tid < 255) ? scanb[tid + 1] : 0u;
        if (incl >= want && abov < want) {
            sh_sel  = pref | ((u32)tid << shift);
            sh_want = want - abov;
        }
        __syncthreads();
    }
    const u32 tkey = sh_sel;

    u32 my = 0;
    for (int it = 0; it < N / 256; ++it) my += (keys[it * 256 + tid] > tkey) ? 1u : 0u;
    atomicAdd(&sh_gt, my);
    __syncthreads();
    const int m = K1 - (int)sh_gt;     // ties to accept, >= 1

    // binary search smallest X with #(ties at idx<=X) >= m  -> L = X
    int lo = 0, hi = N - 1;
    while (lo < hi) {
        int mid = (lo + hi) >> 1;
        if (tid == 0) sh_cnt = 0u;
        __syncthreads();
        u32 c = 0;
        for (int it = 0; it < N / 256; ++it) {
            int j = it * 256 + tid;
            c += (keys[j] == tkey && j <= mid) ? 1u : 0u;
        }
        atomicAdd(&sh_cnt, c);
        __syncthreads();
        if ((int)sh_cnt >= m) hi = mid; else lo = mid + 1;
        __syncthreads();               // protect sh_cnt reuse
    }
    if (tid == 0) { t_out[blockIdx.x] = tkey; L_out[blockIdx.x] = lo; }
}

// ============================================================================
// 6) scatter: out rows were pre-zeroed by extract. For each row, re-check its
//    candidates against row AND col thresholds and write the <=31 survivors.
//    Correctness: for unflagged rows, tk_r >= g, and rowcand holds ALL
//    entries with key >= g -> every survivor is in rowcand. Flagged rows
//    (rare) re-scan the full row of A.
// ============================================================================
__global__ __launch_bounds__(256) void scatter_kernel(
        const float* __restrict__ A,
        const u64* __restrict__ rowcand, const u32* __restrict__ rowcnt,
        const u32* __restrict__ rowflg,
        const u32* __restrict__ tk_r, const int* __restrict__ L_r,
        const u32* __restrict__ tk_c, const int* __restrict__ L_c,
        float* __restrict__ out) {
    const int i   = blockIdx.x;
    const int tid = threadIdx.x;
    const u32 tr = tk_r[i];
    const int lr = L_r[i];
    if (rowflg[i] == 0u) {
        const u32 cnt = rowcnt[i];               // <= CAP (else flagged)
        for (u32 s = tid; s < cnt; s += 256) {
            const u64 e = rowcand[(size_t)i * CAP + s];
            const u32 k = (u32)(e >> 32);
            const int j = (int)(~(u32)e);
            bool rok = (k > tr) || (k == tr && j <= lr);
            if (!rok) continue;
            const u32 tcv = tk_c[j];
            const int lcv = L_c[j];
            bool cok = (k > tcv) || (k == tcv && i <= lcv);
            if (cok && i != j)
                out[(size_t)i * N + j] = __uint_as_float(fkey_inv(k));
        }
    } else {
        // rare: full row re-scan (thresholds may be below g)
        const uint4* A4 = (const uint4*)(A + (size_t)i * N);
        for (int it = 0; it < 8; ++it) {
            uint4 v = A4[it * 256 + tid];
            const int j0 = (it * 256 + tid) * 4;
            u32 bs[4] = { v.x, v.y, v.z, v.w };
#pragma unroll
            for (int q = 0; q < 4; ++q) {
                const int j = j0 + q;
                const u32 k = fkey(bs[q]);
                bool rok = (k > tr) || (k == tr && j <= lr);
                if (!rok) continue;
                const u32 tcv = tk_c[j];
                const int lcv = L_c[j];
                bool cok = (k > tcv) || (k == tcv && i <= lcv);
                if (cok && i != j)
                    out[(size_t)i * N + j] = __uint_as_float(bs[q]);
            }
        }
    }
}

// ============================================================================
extern "C" void kernel_launch(void* const* d_in, const int* in_sizes, int n_in,
                              void* d_out, int out_size, void* d_ws, size_t ws_size,
                              hipStream_t stream) {
    const float* A   = (const float*)d_in[0];
    float*       out = (float*)d_out;

    // ---- everything lives in ws (~129.3 MB of the 1 GiB workspace) ----
    u64* rowcand    = (u64*)d_ws;                                // 64 MB
    u64* colcand    = rowcand + (size_t)N * CAP;                 // 64 MB
    u32* colcnt_pad = (u32*)(colcand + (size_t)N * CAP);         // 512 KB
    u32* hist       = colcnt_pad + (size_t)N * CSTRIDE;          // NB
    u32* g_key      = hist + NB;                                 // 1 (+pad to 64)
    u32* rowcnt     = g_key + 64;                                // N
    u32* rowflg     = rowcnt + N;                                // N
    u32* colflg     = rowflg + N;                                // N
    u32* tk_r       = colflg + N;                                // N
    int* L_r        = (int*)(tk_r + N);                          // N
    u32* tk_c       = (u32*)(L_r + N);                           // N
    int* L_c        = (int*)(tk_c + N);                          // N

    init_kernel<<<dim3(128), dim3(256), 0, stream>>>(hist, colcnt_pad);
    sample_hist_kernel<<<dim3(256), dim3(256), 0, stream>>>(A, hist);
    pick_g_kernel<<<dim3(1), dim3(256), 0, stream>>>(hist, g_key);
    extract_kernel<<<dim3(N), dim3(256), 0, stream>>>(A, g_key, rowcand, colcand,
                                                      rowcnt, colcnt_pad, out);
    rank_select_kernel<<<dim3(N), dim3(256), 0, stream>>>(rowcand, rowcnt, 1, tk_r, L_r, rowflg);
    rank_select_kernel<<<dim3(N), dim3(256), 0, stream>>>(colcand, colcnt_pad, CSTRIDE, tk_c, L_c, colflg);
    fallback_select_kernel<<<dim3(N), dim3(256), 0, stream>>>(A, rowflg, (long)N, 1L, tk_r, L_r);
    fallback_select_kernel<<<dim3(N), dim3(256), 0, stream>>>(A, colflg, 1L, (long)N, tk_c, L_c);
    scatter_kernel<<<dim3(N), dim3(256), 0, stream>>>(A, rowcand, rowcnt, rowflg,
                                                      tk_r, L_r, tk_c, L_c, out);
}

// Round 4
// 535.485 us; speedup vs baseline: 1.2036x; 1.0138x over previous
//
#include <hip/hip_runtime.h>

#define N 8192
#define K1 31              // K=30 -> k+1 = 31 kept per row/column
#define CAP 1024           // candidate capacity per line (row or col)
#define WCAP 512           // per-wave LDS candidate buffer (expected ~47 hits/wave)
#define NB 2048            // global histogram bins (top 11 key bits)
#define HSHIFT 21
#define TARGET 76800u      // sampled suffix target; 4M samples, ~1.83% suffix (~186/line)
#define CSTRIDE 16         // colcnt padded: one u32 counter per 64B line

typedef unsigned int u32;
typedef unsigned long long u64;

// monotone fp32-bits -> u32 key (larger float => larger key)
__device__ __forceinline__ u32 fkey(u32 u) {
    return (u & 0x80000000u) ? ~u : (u | 0x80000000u);
}
// inverse of fkey (exact bit recovery of the original float)
__device__ __forceinline__ u32 fkey_inv(u32 k) {
    return (k & 0x80000000u) ? (k ^ 0x80000000u) : ~k;
}
// pack (key, idx): larger u64 = larger key, or equal key and SMALLER idx
__device__ __forceinline__ u64 pack_ki(u32 key, u32 idx) {
    return ((u64)key << 32) | (u32)(~idx);
}

// ============================================================================
// 0) zero: hist, padded col counters, row counters (atomic-accumulated now),
//    pre-flags.
// ============================================================================
__global__ __launch_bounds__(256) void init_kernel(u32* __restrict__ hist,
                                                   u32* __restrict__ colcnt_pad,
                                                   u32* __restrict__ rowcnt,
                                                   u32* __restrict__ preflg) {
    const int i = blockIdx.x * 256 + threadIdx.x;
    const int gs = (int)gridDim.x * 256;
    if (i < NB) hist[i] = 0u;
    for (int j = i; j < N * CSTRIDE; j += gs) colcnt_pad[j] = 0u;
    for (int j = i; j < N; j += gs) rowcnt[j] = 0u;
    for (int j = i; j < 2 * N; j += gs) preflg[j] = 0u;
}

// ============================================================================
// 1) sampled global histogram: 4M samples as coalesced float4 runs.
//    4096 runs of 256 uint4 (4 KB contiguous each), rotated within each
//    64 KB segment so all column groups are covered. 4-way LDS sub-hists.
// ============================================================================
__global__ __launch_bounds__(256) void sample_hist_kernel(const float* __restrict__ A,
                                                          u32* __restrict__ hist) {
    __shared__ u32 h[4][NB];
    const int tid = threadIdx.x;
    for (int b = tid; b < 4 * NB; b += 256) ((u32*)h)[b] = 0u;
    __syncthreads();
    const int sub = tid & 3;
    const uint4* A4 = (const uint4*)A;
#pragma unroll
    for (int it = 0; it < 16; ++it) {
        const int run = blockIdx.x * 16 + it;                       // 0..4095
        const size_t idx = (size_t)run * 4096 + (size_t)((run & 15) * 256) + tid;
        uint4 v = A4[idx];                                          // coalesced
        atomicAdd(&h[sub][fkey(v.x) >> HSHIFT], 1u);
        atomicAdd(&h[sub][fkey(v.y) >> HSHIFT], 1u);
        atomicAdd(&h[sub][fkey(v.z) >> HSHIFT], 1u);
        atomicAdd(&h[sub][fkey(v.w) >> HSHIFT], 1u);
    }
    __syncthreads();
    for (int b = tid; b < NB; b += 256) {
        u32 s = h[0][b] + h[1][b] + h[2][b] + h[3][b];
        if (s) atomicAdd(&hist[b], s);
    }
}

// ============================================================================
// 2) pick conservative global key threshold g: largest bin base with
//    sampled suffix count >= TARGET. One block.
// ============================================================================
__global__ __launch_bounds__(256) void pick_g_kernel(const u32* __restrict__ hist,
                                                     u32* __restrict__ g_out) {
    __shared__ u32 suf[NB + 1];
    __shared__ u32 part[256];
    const int tid = threadIdx.x;
    u32 loc[8];
    u32 s = 0;
    for (int k = 7; k >= 0; --k) { s += hist[tid * 8 + k]; loc[k] = s; }
    part[tid] = s;
    __syncthreads();
    for (int off = 1; off < 256; off <<= 1) {        // inclusive suffix scan
        u32 add = (tid + off < 256) ? part[tid + off] : 0u;
        __syncthreads();
        part[tid] += add;
        __syncthreads();
    }
    u32 higher = (tid < 255) ? part[tid + 1] : 0u;
    for (int k = 0; k < 8; ++k) suf[tid * 8 + k] = loc[k] + higher;
    if (tid == 0) suf[NB] = 0u;
    __syncthreads();
    for (int k = 0; k < 8; ++k) {
        int b = tid * 8 + k;
        if (suf[b] >= TARGET && suf[b + 1] < TARGET)   // exactly one b (suf monotone)
            *g_out = (u32)b << HSHIFT;
    }
}

// ============================================================================
// 3) barrier-free streaming extraction + out pre-zero. One block per row,
//    each wave owns a contiguous quarter: private LDS buffer + LDS counter
//    (no cross-wave traffic, no __syncthreads in the hot path -> no vmcnt(0)
//    drains). Flush: one device atomicAdd per wave reserves a packed segment
//    of rowcand (order-agnostic downstream); col entries emitted per hit.
//    Wave-buffer overflow (>WCAP hits, ~impossible) pre-flags the row and
//    emits the col entry inline, so counts stay exact.
// ============================================================================
__global__ __launch_bounds__(256) void extract_kernel(
        const float* __restrict__ A, const u32* __restrict__ g_ptr,
        u64* __restrict__ rowcand, u64* __restrict__ colcand,
        u32* __restrict__ rowcnt, u32* __restrict__ colcnt_pad,
        u32* __restrict__ preflg, float* __restrict__ out) {
    __shared__ u64 buf[4][WCAP];
    __shared__ u32 wc[4];
    const int tid  = threadIdx.x;
    const int lane = tid & 63;
    const int w    = tid >> 6;
    const int row  = blockIdx.x;
    if (tid < 4) wc[tid] = 0u;
    __syncthreads();                                  // once, before any loads
    const u32 g = *g_ptr;
    const uint4* A4 = (const uint4*)(A + (size_t)row * N);
    uint4* O4 = (uint4*)(out + (size_t)row * N);
    uint4 v[8];
#pragma unroll
    for (int it = 0; it < 8; ++it) v[it] = A4[w * 512 + it * 64 + lane];  // 8 in flight
    const uint4 z = make_uint4(0u, 0u, 0u, 0u);
#pragma unroll
    for (int it = 0; it < 8; ++it) O4[w * 512 + it * 64 + lane] = z;      // pre-zero out
#pragma unroll
    for (int it = 0; it < 8; ++it) {
        const int j = (w * 512 + it * 64 + lane) * 4;
        u32 ks[4] = { fkey(v[it].x), fkey(v[it].y), fkey(v[it].z), fkey(v[it].w) };
#pragma unroll
        for (int q = 0; q < 4; ++q) {
            if (ks[q] >= g) {
                u32 slot = atomicAdd(&wc[w], 1u);     // wave-private LDS counter
                if (slot < WCAP) {
                    buf[w][slot] = pack_ki(ks[q], (u32)(j + q));
                } else {
                    // wave buffer overflow: flag row, emit col entry inline
                    atomicOr(&preflg[row], 1u);
                    const int c = j + q;
                    u32 cs = atomicAdd(&colcnt_pad[(size_t)c * CSTRIDE], 1u);
                    if (cs < CAP) colcand[(size_t)c * CAP + cs] = pack_ki(ks[q], (u32)row);
                }
            }
        }
    }
    // per-wave flush (no block barrier): reserve packed segment, emit entries
    const u32 cw = wc[w];                             // same-wave DS ordering
    const u32 stored = cw < (u32)WCAP ? cw : (u32)WCAP;
    u32 base = 0u;
    if (lane == 0) base = atomicAdd(&rowcnt[row], cw);  // exact total for flags
    base = __shfl(base, 0);
    for (u32 i = lane; i < stored; i += 64) {
        const u64 e = buf[w][i];
        const u32 key = (u32)(e >> 32);
        const u32 c   = ~(u32)e;
        if (base + i < (u32)CAP) rowcand[(size_t)row * CAP + base + i] = e;
        u32 cs = atomicAdd(&colcnt_pad[(size_t)c * CSTRIDE], 1u);
        if (cs < CAP) colcand[(size_t)c * CAP + cs] = pack_ki(key, (u32)row);
    }
}

// ============================================================================
// 4) merged exact select (2N blocks: b<N rows, else cols): 31st-largest
//    (key,idx) via pairwise rank over the candidate list. Flags lines
//    needing the fallback (preflagged, cnt<31, or cnt>CAP).
// ============================================================================
__global__ __launch_bounds__(256) void rank_select_kernel(
        const u64* __restrict__ rowcand, const u64* __restrict__ colcand,
        const u32* __restrict__ rowcnt, const u32* __restrict__ colcnt_pad,
        const u32* __restrict__ preflg,
        u32* __restrict__ tk, int* __restrict__ L, u32* __restrict__ flag) {
    __shared__ u64 buf[CAP];
    const int b   = blockIdx.x;
    const int tid = threadIdx.x;
    const bool isrow = b < N;
    const u64* cand = isrow ? rowcand + (size_t)b * CAP
                            : colcand + (size_t)(b - N) * CAP;
    const u32 cnt = isrow ? rowcnt[b] : colcnt_pad[(size_t)(b - N) * CSTRIDE];
    if (preflg[b] != 0u || cnt < (u32)K1 || cnt > (u32)CAP) {
        if (tid == 0) flag[b] = 1u;
        return;
    }
    if (tid == 0) flag[b] = 0u;
    for (u32 s = tid; s < cnt; s += 256) buf[s] = cand[s];
    __syncthreads();
    for (u32 s = tid; s < cnt; s += 256) {
        const u64 mine = buf[s];
        u32 r = 0;
        for (u32 q = 0; q < cnt; ++q) r += (buf[q] > mine) ? 1u : 0u;  // LDS broadcast
        if (r == (u32)(K1 - 1)) {
            tk[b] = (u32)(mine >> 32);
            L[b]  = (int)(~(u32)mine);
        }
    }
}

// ============================================================================
// 5) merged exact fallback (2N blocks, rare: early-exits on clear flag).
//    Full LDS radix-256 select over 32-bit keys + binary-searched tie
//    index L. b<N: row b (stride 1); else: column b-N (stride N).
// ============================================================================
__global__ __launch_bounds__(256) void fallback_select_kernel(
        const float* __restrict__ A, const u32* __restrict__ flag,
        u32* __restrict__ tk, int* __restrict__ L_out) {
    if (flag[blockIdx.x] == 0u) return;
    __shared__ u32 keys[N];            // 32 KB
    __shared__ u32 hist[4][256];
    __shared__ u32 scanb[256];
    __shared__ u32 sh_sel, sh_want, sh_gt, sh_cnt;

    const int b    = blockIdx.x;
    const int tid  = threadIdx.x;
    const int wave = tid >> 6;
    const bool isrow = b < N;
    const size_t base    = isrow ? (size_t)b * N : (size_t)(b - N);
    const size_t estride = isrow ? 1 : (size_t)N;

    for (int it = 0; it < N / 256; ++it) {
        int j = it * 256 + tid;
        keys[j] = fkey(__float_as_uint(A[base + (size_t)j * estride]));
    }
    if (tid == 0) { sh_sel = 0u; sh_want = (u32)K1; sh_gt = 0u; }
    __syncthreads();

    for (int pass = 3; pass >= 0; --pass) {
        const u32 pref = sh_sel;
        const u32 want = sh_want;
        hist[0][tid] = 0u; hist[1][tid] = 0u; hist[2][tid] = 0u; hist[3][tid] = 0u;
        __syncthreads();
        const u32 pmask = (pass == 3) ? 0u : (0xFFFFFFFFu << ((pass + 1) * 8));
        const int shift = pass * 8;
        for (int it = 0; it < N / 256; ++it) {
            u32 k = keys[it * 256 + tid];
            if ((k & pmask) == (pref & pmask))
                atomicAdd(&hist[wave][(k >> shift) & 0xFFu], 1u);
        }
        __syncthreads();
        scanb[tid] = hist[0][tid] + hist[1][tid] + hist[2][tid] + hist[3][tid];
        __syncthreads();
        for (int off = 1; off < 256; off <<= 1) {
            u32 add = (tid + off < 256) ? scanb[tid + off] : 0u;
            __syncthreads();
            scanb[tid] += add;
            __syncthreads();
        }
        u32 incl = scanb[tid];
        u32 abov = (tid < 255) ? scanb[tid + 1] : 0u;
        if (incl >= want && abov < want) {
            sh_sel  = pref | ((u32)tid << shift);
            sh_want = want - abov;
        }
        __syncthreads();
    }
    const u32 tkey = sh_sel;

    u32 my = 0;
    for (int it = 0; it < N / 256; ++it) my += (keys[it * 256 + tid] > tkey) ? 1u : 0u;
    atomicAdd(&sh_gt, my);
    __syncthreads();
    const int m = K1 - (int)sh_gt;     // ties to accept, >= 1

    // binary search smallest X with #(ties at idx<=X) >= m  -> L = X
    int lo = 0, hi = N - 1;
    while (lo < hi) {
        int mid = (lo + hi) >> 1;
        if (tid == 0) sh_cnt = 0u;
        __syncthreads();
        u32 c = 0;
        for (int it = 0; it < N / 256; ++it) {
            int j = it * 256 + tid;
            c += (keys[j] == tkey && j <= mid) ? 1u : 0u;
        }
        atomicAdd(&sh_cnt, c);
        __syncthreads();
        if ((int)sh_cnt >= m) hi = mid; else lo = mid + 1;
        __syncthreads();               // protect sh_cnt reuse
    }
    if (tid == 0) { tk[b] = tkey; L_out[b] = lo; }
}

// ============================================================================
// 6) scatter: out rows were pre-zeroed by extract. For each row, re-check its
//    candidates against row AND col thresholds and write the <=31 survivors.
//    Correctness: unflagged rows have tk_row >= g and a complete, packed
//    rowcand -> every survivor is present. Flagged rows re-scan A.
// ============================================================================
__global__ __launch_bounds__(256) void scatter_kernel(
        const float* __restrict__ A,
        const u64* __restrict__ rowcand, const u32* __restrict__ rowcnt,
        const u32* __restrict__ flag,
        const u32* __restrict__ tk, const int* __restrict__ L,
        float* __restrict__ out) {
    const int i   = blockIdx.x;
    const int tid = threadIdx.x;
    const u32 tr = tk[i];
    const int lr = L[i];
    if (flag[i] == 0u) {
        const u32 cnt = rowcnt[i];               // <= CAP (else flagged)
        for (u32 s = tid; s < cnt; s += 256) {
            const u64 e = rowcand[(size_t)i * CAP + s];
            const u32 k = (u32)(e >> 32);
            const int j = (int)(~(u32)e);
            bool rok = (k > tr) || (k == tr && j <= lr);
            if (!rok) continue;
            const u32 tcv = tk[N + j];
            const int lcv = L[N + j];
            bool cok = (k > tcv) || (k == tcv && i <= lcv);
            if (cok && i != j)
                out[(size_t)i * N + j] = __uint_as_float(fkey_inv(k));
        }
    } else {
        // rare: full row re-scan (thresholds may be below g)
        const uint4* A4 = (const uint4*)(A + (size_t)i * N);
        for (int it = 0; it < 8; ++it) {
            uint4 v = A4[it * 256 + tid];
            const int j0 = (it * 256 + tid) * 4;
            u32 bs[4] = { v.x, v.y, v.z, v.w };
#pragma unroll
            for (int q = 0; q < 4; ++q) {
                const int j = j0 + q;
                const u32 k = fkey(bs[q]);
                bool rok = (k > tr) || (k == tr && j <= lr);
                if (!rok) continue;
                const u32 tcv = tk[N + j];
                const int lcv = L[N + j];
                bool cok = (k > tcv) || (k == tcv && i <= lcv);
                if (cok && i != j)
                    out[(size_t)i * N + j] = __uint_as_float(bs[q]);
            }
        }
    }
}

// ============================================================================
extern "C" void kernel_launch(void* const* d_in, const int* in_sizes, int n_in,
                              void* d_out, int out_size, void* d_ws, size_t ws_size,
                              hipStream_t stream) {
    const float* A   = (const float*)d_in[0];
    float*       out = (float*)d_out;

    // ---- everything lives in ws (~129.4 MB of the 1 GiB workspace) ----
    u64* rowcand    = (u64*)d_ws;                                // 64 MB
    u64* colcand    = rowcand + (size_t)N * CAP;                 // 64 MB
    u32* colcnt_pad = (u32*)(colcand + (size_t)N * CAP);         // 512 KB
    u32* hist       = colcnt_pad + (size_t)N * CSTRIDE;          // NB
    u32* g_key      = hist + NB;                                 // 1 (+pad to 64)
    u32* rowcnt     = g_key + 64;                                // N
    u32* preflg     = rowcnt + N;                                // 2N
    u32* flag       = preflg + 2 * N;                            // 2N
    u32* tk         = flag + 2 * N;                              // 2N
    int* L          = (int*)(tk + 2 * N);                        // 2N

    init_kernel<<<dim3(128), dim3(256), 0, stream>>>(hist, colcnt_pad, rowcnt, preflg);
    sample_hist_kernel<<<dim3(256), dim3(256), 0, stream>>>(A, hist);
    pick_g_kernel<<<dim3(1), dim3(256), 0, stream>>>(hist, g_key);
    extract_kernel<<<dim3(N), dim3(256), 0, stream>>>(A, g_key, rowcand, colcand,
                                                      rowcnt, colcnt_pad, preflg, out);
    rank_select_kernel<<<dim3(2 * N), dim3(256), 0, stream>>>(rowcand, colcand, rowcnt,
                                                              colcnt_pad, preflg, tk, L, flag);
    fallback_select_kernel<<<dim3(2 * N), dim3(256), 0, stream>>>(A, flag, tk, L);
    scatter_kernel<<<dim3(N), dim3(256), 0, stream>>>(A, rowcand, rowcnt, flag, tk, L, out);
}

// Round 7
// 499.215 us; speedup vs baseline: 1.2910x; 1.0727x over previous
//
#include <hip/hip_runtime.h>

#define N 8192
#define K1 31              // K=30 -> k+1 = 31 kept per row/column
#define CAP 256            // candidate capacity per line (lambda ~72-100, P(>256)~0)
#define WCAP 256           // per-wave LDS candidate buffer (~18 expected hits/wave)
#define NB 8192            // global histogram bins (top 13 key bits: 4 mantissa bits)
#define HSHIFT 19
#define TARGET 36000u      // sampled suffix target: 0.90% of 4M -> lambda ~72-100/line
#define CSTRIDE 16         // colcnt padded: one u32 counter per 64B line

typedef unsigned int u32;
typedef unsigned long long u64;
typedef u32 u32x4 __attribute__((ext_vector_type(4)));   // native vector for NT builtins

// monotone fp32-bits -> u32 key (larger float => larger key)
__device__ __forceinline__ u32 fkey(u32 u) {
    return (u & 0x80000000u) ? ~u : (u | 0x80000000u);
}
// inverse of fkey (exact bit recovery of the original float)
__device__ __forceinline__ u32 fkey_inv(u32 k) {
    return (k & 0x80000000u) ? (k ^ 0x80000000u) : ~k;
}
// pack (key, idx): larger u64 = larger key, or equal key and SMALLER idx
__device__ __forceinline__ u64 pack_ki(u32 key, u32 idx) {
    return ((u64)key << 32) | (u32)(~idx);
}

// ============================================================================
// 0) zero: hist, padded col counters, row counters, pre-flags
// ============================================================================
__global__ __launch_bounds__(256) void init_kernel(u32* __restrict__ hist,
                                                   u32* __restrict__ colcnt_pad,
                                                   u32* __restrict__ rowcnt,
                                                   u32* __restrict__ preflg) {
    const int i = blockIdx.x * 256 + threadIdx.x;
    const int gs = (int)gridDim.x * 256;
    for (int j = i; j < NB; j += gs) hist[j] = 0u;
    for (int j = i; j < N * CSTRIDE; j += gs) colcnt_pad[j] = 0u;
    for (int j = i; j < N; j += gs) rowcnt[j] = 0u;
    for (int j = i; j < 2 * N; j += gs) preflg[j] = 0u;
}

// ============================================================================
// 1) sampled global histogram: 4M samples as coalesced float4 runs.
//    4096 runs of 256 uint4 (4 KB contiguous each), rotated within each
//    64 KB segment so all column groups are covered. Single 32 KB LDS hist
//    (8192 bins -> LDS atomic collisions negligible).
// ============================================================================
__global__ __launch_bounds__(256) void sample_hist_kernel(const float* __restrict__ A,
                                                          u32* __restrict__ hist) {
    __shared__ u32 h[NB];
    const int tid = threadIdx.x;
    for (int b = tid; b < NB; b += 256) h[b] = 0u;
    __syncthreads();
    const uint4* A4 = (const uint4*)A;
#pragma unroll
    for (int it = 0; it < 16; ++it) {
        const int run = blockIdx.x * 16 + it;                       // 0..4095
        const size_t idx = (size_t)run * 4096 + (size_t)((run & 15) * 256) + tid;
        uint4 v = A4[idx];                                          // coalesced
        atomicAdd(&h[fkey(v.x) >> HSHIFT], 1u);
        atomicAdd(&h[fkey(v.y) >> HSHIFT], 1u);
        atomicAdd(&h[fkey(v.z) >> HSHIFT], 1u);
        atomicAdd(&h[fkey(v.w) >> HSHIFT], 1u);
    }
    __syncthreads();
    for (int b = tid; b < NB; b += 256)
        if (h[b]) atomicAdd(&hist[b], h[b]);
}

// ============================================================================
// 2) pick conservative global key threshold g: largest bin base with
//    sampled suffix count >= TARGET. One block, 32 bins/thread.
// ============================================================================
__global__ __launch_bounds__(256) void pick_g_kernel(const u32* __restrict__ hist,
                                                     u32* __restrict__ g_out) {
    __shared__ u32 suf[NB + 1];
    __shared__ u32 part[256];
    const int tid = threadIdx.x;
    u32 loc[32];
    u32 s = 0;
    for (int k = 31; k >= 0; --k) { s += hist[tid * 32 + k]; loc[k] = s; }
    part[tid] = s;
    __syncthreads();
    for (int off = 1; off < 256; off <<= 1) {        // inclusive suffix scan
        u32 add = (tid + off < 256) ? part[tid + off] : 0u;
        __syncthreads();
        part[tid] += add;
        __syncthreads();
    }
    u32 higher = (tid < 255) ? part[tid + 1] : 0u;
    for (int k = 0; k < 32; ++k) suf[tid * 32 + k] = loc[k] + higher;
    if (tid == 0) suf[NB] = 0u;
    __syncthreads();
    for (int k = 0; k < 32; ++k) {
        int b = tid * 32 + k;
        if (suf[b] >= TARGET && suf[b + 1] < TARGET)   // exactly one b (suf monotone)
            *g_out = (u32)b << HSHIFT;
    }
}

// ============================================================================
// 3) barrier-free streaming extraction + out pre-zero. One block per row,
//    each wave owns a contiguous quarter: private LDS buffer + LDS counter.
//    Nontemporal load of A / store of zeros (single-use streams, keep L2 for
//    candidate structures) via native ext_vector_type (HIP uint4 is a class,
//    rejected by the NT builtins). Flush: one device atomicAdd per wave
//    reserves a packed rowcand segment; col entries emitted per hit.
//    Overflow paths (wave>WCAP) pre-flag the row and emit col entries
//    inline -> exact counts.
// ============================================================================
__global__ __launch_bounds__(256) void extract_kernel(
        const float* __restrict__ A, const u32* __restrict__ g_ptr,
        u64* __restrict__ rowcand, u64* __restrict__ colcand,
        u32* __restrict__ rowcnt, u32* __restrict__ colcnt_pad,
        u32* __restrict__ preflg, float* __restrict__ out) {
    __shared__ u64 buf[4][WCAP];
    __shared__ u32 wc[4];
    const int tid  = threadIdx.x;
    const int lane = tid & 63;
    const int w    = tid >> 6;
    const int row  = blockIdx.x;
    if (tid < 4) wc[tid] = 0u;
    __syncthreads();                                  // once, before any loads
    const u32 g = *g_ptr;
    const u32x4* A4 = (const u32x4*)(A + (size_t)row * N);
    u32x4* O4 = (u32x4*)(out + (size_t)row * N);
    u32x4 v[8];
#pragma unroll
    for (int it = 0; it < 8; ++it)
        v[it] = __builtin_nontemporal_load(&A4[w * 512 + it * 64 + lane]);  // 8 in flight
    const u32x4 z = (u32x4)(0u);
#pragma unroll
    for (int it = 0; it < 8; ++it)
        __builtin_nontemporal_store(z, &O4[w * 512 + it * 64 + lane]);      // pre-zero out
#pragma unroll
    for (int it = 0; it < 8; ++it) {
        const int j = (w * 512 + it * 64 + lane) * 4;
        u32 ks[4] = { fkey(v[it].x), fkey(v[it].y), fkey(v[it].z), fkey(v[it].w) };
#pragma unroll
        for (int q = 0; q < 4; ++q) {
            if (ks[q] >= g) {
                u32 slot = atomicAdd(&wc[w], 1u);     // wave-private LDS counter
                if (slot < WCAP) {
                    buf[w][slot] = pack_ki(ks[q], (u32)(j + q));
                } else {
                    // wave buffer overflow (~impossible): flag row, emit col inline
                    atomicOr(&preflg[row], 1u);
                    const int c = j + q;
                    u32 cs = atomicAdd(&colcnt_pad[(size_t)c * CSTRIDE], 1u);
                    if (cs < CAP) colcand[(size_t)c * CAP + cs] = pack_ki(ks[q], (u32)row);
                }
            }
        }
    }
    // per-wave flush (no block barrier): reserve packed segment, emit entries
    const u32 cw = wc[w];                             // same-wave DS ordering
    const u32 stored = cw < (u32)WCAP ? cw : (u32)WCAP;
    u32 base = 0u;
    if (lane == 0) base = atomicAdd(&rowcnt[row], cw);  // exact total for flags
    base = __shfl(base, 0);
    for (u32 i = lane; i < stored; i += 64) {
        const u64 e = buf[w][i];
        const u32 key = (u32)(e >> 32);
        const u32 c   = ~(u32)e;
        if (base + i < (u32)CAP) rowcand[(size_t)row * CAP + base + i] = e;
        u32 cs = atomicAdd(&colcnt_pad[(size_t)c * CSTRIDE], 1u);
        if (cs < CAP) colcand[(size_t)c * CAP + cs] = pack_ki(key, (u32)row);
    }
}

// ============================================================================
// 4) merged exact select (2N blocks: b<N rows, else cols): 31st-largest
//    (key,idx) via pairwise rank over the candidate list. Flags lines
//    needing the fallback (preflagged, cnt<31, or cnt>CAP).
// ============================================================================
__global__ __launch_bounds__(256) void rank_select_kernel(
        const u64* __restrict__ rowcand, const u64* __restrict__ colcand,
        const u32* __restrict__ rowcnt, const u32* __restrict__ colcnt_pad,
        const u32* __restrict__ preflg,
        u32* __restrict__ tk, int* __restrict__ L, u32* __restrict__ flag) {
    __shared__ u64 buf[CAP];
    const int b   = blockIdx.x;
    const int tid = threadIdx.x;
    const bool isrow = b < N;
    const u64* cand = isrow ? rowcand + (size_t)b * CAP
                            : colcand + (size_t)(b - N) * CAP;
    const u32 cnt = isrow ? rowcnt[b] : colcnt_pad[(size_t)(b - N) * CSTRIDE];
    if (preflg[b] != 0u || cnt < (u32)K1 || cnt > (u32)CAP) {
        if (tid == 0) flag[b] = 1u;
        return;
    }
    if (tid == 0) flag[b] = 0u;
    if (tid < (int)cnt) buf[tid] = cand[tid];        // cnt <= CAP = 256
    __syncthreads();
    if (tid < (int)cnt) {
        const u64 mine = buf[tid];
        u32 r = 0;
        for (u32 q = 0; q < cnt; ++q) r += (buf[q] > mine) ? 1u : 0u;  // LDS broadcast
        if (r == (u32)(K1 - 1)) {
            tk[b] = (u32)(mine >> 32);
            L[b]  = (int)(~(u32)mine);
        }
    }
}

// ============================================================================
// 5) merged exact fallback (2N blocks, rare: early-exits on clear flag).
//    Full LDS radix-256 select over 32-bit keys + binary-searched tie
//    index L. b<N: row b (stride 1); else: column b-N (stride N).
// ============================================================================
__global__ __launch_bounds__(256) void fallback_select_kernel(
        const float* __restrict__ A, const u32* __restrict__ flag,
        u32* __restrict__ tk, int* __restrict__ L_out) {
    if (flag[blockIdx.x] == 0u) return;
    __shared__ u32 keys[N];            // 32 KB
    __shared__ u32 hist[4][256];
    __shared__ u32 scanb[256];
    __shared__ u32 sh_sel, sh_want, sh_gt, sh_cnt;

    const int b    = blockIdx.x;
    const int tid  = threadIdx.x;
    const int wave = tid >> 6;
    const bool isrow = b < N;
    const size_t base    = isrow ? (size_t)b * N : (size_t)(b - N);
    const size_t estride = isrow ? 1 : (size_t)N;

    for (int it = 0; it < N / 256; ++it) {
        int j = it * 256 + tid;
        keys[j] = fkey(__float_as_uint(A[base + (size_t)j * estride]));
    }
    if (tid == 0) { sh_sel = 0u; sh_want = (u32)K1; sh_gt = 0u; }
    __syncthreads();

    for (int pass = 3; pass >= 0; --pass) {
        const u32 pref = sh_sel;
        const u32 want = sh_want;
        hist[0][tid] = 0u; hist[1][tid] = 0u; hist[2][tid] = 0u; hist[3][tid] = 0u;
        __syncthreads();
        const u32 pmask = (pass == 3) ? 0u : (0xFFFFFFFFu << ((pass + 1) * 8));
        const int shift = pass * 8;
        for (int it = 0; it < N / 256; ++it) {
            u32 k = keys[it * 256 + tid];
            if ((k & pmask) == (pref & pmask))
                atomicAdd(&hist[wave][(k >> shift) & 0xFFu], 1u);
        }
        __syncthreads();
        scanb[tid] = hist[0][tid] + hist[1][tid] + hist[2][tid] + hist[3][tid];
        __syncthreads();
        for (int off = 1; off < 256; off <<= 1) {
            u32 add = (tid + off < 256) ? scanb[tid + off] : 0u;
            __syncthreads();
            scanb[tid] += add;
            __syncthreads();
        }
        u32 incl = scanb[tid];
        u32 abov = (tid < 255) ? scanb[tid + 1] : 0u;
        if (incl >= want && abov < want) {
            sh_sel  = pref | ((u32)tid << shift);
            sh_want = want - abov;
        }
        __syncthreads();
    }
    const u32 tkey = sh_sel;

    u32 my = 0;
    for (int it = 0; it < N / 256; ++it) my += (keys[it * 256 + tid] > tkey) ? 1u : 0u;
    atomicAdd(&sh_gt, my);
    __syncthreads();
    const int m = K1 - (int)sh_gt;     // ties to accept, >= 1

    // binary search smallest X with #(ties at idx<=X) >= m  -> L = X
    int lo = 0, hi = N - 1;
    while (lo < hi) {
        int mid = (lo + hi) >> 1;
        if (tid == 0) sh_cnt = 0u;
        __syncthreads();
        u32 c = 0;
        for (int it = 0; it < N / 256; ++it) {
            int j = it * 256 + tid;
            c += (keys[j] == tkey && j <= mid) ? 1u : 0u;
        }
        atomicAdd(&sh_cnt, c);
        __syncthreads();
        if ((int)sh_cnt >= m) hi = mid; else lo = mid + 1;
        __syncthreads();               // protect sh_cnt reuse
    }
    if (tid == 0) { tk[b] = tkey; L_out[b] = lo; }
}

// ============================================================================
// 6) scatter: out rows were pre-zeroed by extract. For each row, re-check its
//    candidates against row AND col thresholds and write the <=31 survivors.
//    Correctness: unflagged rows have tk_row >= g and a complete, packed
//    rowcand -> every survivor is present. Flagged rows re-scan A.
// ============================================================================
__global__ __launch_bounds__(256) void scatter_kernel(
        const float* __restrict__ A,
        const u64* __restrict__ rowcand, const u32* __restrict__ rowcnt,
        const u32* __restrict__ flag,
        const u32* __restrict__ tk, const int* __restrict__ L,
        float* __restrict__ out) {
    const int i   = blockIdx.x;
    const int tid = threadIdx.x;
    const u32 tr = tk[i];
    const int lr = L[i];
    if (flag[i] == 0u) {
        const u32 cnt = rowcnt[i];               // <= CAP (else flagged)
        if (tid < (int)cnt) {
            const u64 e = rowcand[(size_t)i * CAP + tid];
            const u32 k = (u32)(e >> 32);
            const int j = (int)(~(u32)e);
            bool rok = (k > tr) || (k == tr && j <= lr);
            if (rok) {
                const u32 tcv = tk[N + j];
                const int lcv = L[N + j];
                bool cok = (k > tcv) || (k == tcv && i <= lcv);
                if (cok && i != j)
                    out[(size_t)i * N + j] = __uint_as_float(fkey_inv(k));
            }
        }
    } else {
        // rare: full row re-scan (thresholds may be below g)
        const uint4* A4 = (const uint4*)(A + (size_t)i * N);
        for (int it = 0; it < 8; ++it) {
            uint4 v = A4[it * 256 + tid];
            const int j0 = (it * 256 + tid) * 4;
            u32 bs[4] = { v.x, v.y, v.z, v.w };
#pragma unroll
            for (int q = 0; q < 4; ++q) {
                const int j = j0 + q;
                const u32 k = fkey(bs[q]);
                bool rok = (k > tr) || (k == tr && j <= lr);
                if (!rok) continue;
                const u32 tcv = tk[N + j];
                const int lcv = L[N + j];
                bool cok = (k > tcv) || (k == tcv && i <= lcv);
                if (cok && i != j)
                    out[(size_t)i * N + j] = __uint_as_float(bs[q]);
            }
        }
    }
}

// ============================================================================
extern "C" void kernel_launch(void* const* d_in, const int* in_sizes, int n_in,
                              void* d_out, int out_size, void* d_ws, size_t ws_size,
                              hipStream_t stream) {
    const float* A   = (const float*)d_in[0];
    float*       out = (float*)d_out;

    // ---- everything lives in ws (~33.5 MB of the 1 GiB workspace) ----
    u64* rowcand    = (u64*)d_ws;                                // 16 MB
    u64* colcand    = rowcand + (size_t)N * CAP;                 // 16 MB
    u32* colcnt_pad = (u32*)(colcand + (size_t)N * CAP);         // 512 KB
    u32* hist       = colcnt_pad + (size_t)N * CSTRIDE;          // NB
    u32* g_key      = hist + NB;                                 // 1 (+pad to 64)
    u32* rowcnt     = g_key + 64;                                // N
    u32* preflg     = rowcnt + N;                                // 2N
    u32* flag       = preflg + 2 * N;                            // 2N
    u32* tk         = flag + 2 * N;                              // 2N
    int* L          = (int*)(tk + 2 * N);                        // 2N

    init_kernel<<<dim3(128), dim3(256), 0, stream>>>(hist, colcnt_pad, rowcnt, preflg);
    sample_hist_kernel<<<dim3(256), dim3(256), 0, stream>>>(A, hist);
    pick_g_kernel<<<dim3(1), dim3(256), 0, stream>>>(hist, g_key);
    extract_kernel<<<dim3(N), dim3(256), 0, stream>>>(A, g_key, rowcand, colcand,
                                                      rowcnt, colcnt_pad, preflg, out);
    rank_select_kernel<<<dim3(2 * N), dim3(256), 0, stream>>>(rowcand, colcand, rowcnt,
                                                              colcnt_pad, preflg, tk, L, flag);
    fallback_select_kernel<<<dim3(2 * N), dim3(256), 0, stream>>>(A, flag, tk, L);
    scatter_kernel<<<dim3(N), dim3(256), 0, stream>>>(A, rowcand, rowcnt, flag, tk, L, out);
}